// Round 8
// baseline (274.754 us; speedup 1.0000x reference)
//
#include <hip/hip_runtime.h>

#define NSEQ   24
#define NBOX   196
#define NCTX   196
#define MAXLEN 6
#define EPSV   1e-6f
#define BS     32
#define BPB    16            // blocks per batch
#define GRID   (BS * BPB)    // 512
#define THR    512
#define NB4    49            // float4 chunks per 196-row
#define ROWP   200           // padded cae row (196 + 4 zero pad, sentinel idx 196)

// ws layout (4-byte elems): midx[BS*NBOX*NCTX] | araw[MAXLEN*BS*NBOX] |
//                           oldrow[2*BS*NBOX] | cnt[MAXLEN*BS*16] (line-padded)
#define MIDX_ELEMS ((size_t)BS * NBOX * NCTX)
#define CNT_N      (MAXLEN * BS * 16)

__global__ void zero_cnt(unsigned* __restrict__ cnt) {
    int i = blockIdx.x * blockDim.x + threadIdx.x;
    if (i < CNT_N) cnt[i] = 0u;
}

__device__ __forceinline__ float blockmax(float a, float* s_red, int tid) {
    #pragma unroll
    for (int off = 32; off >= 1; off >>= 1)
        a = fmaxf(a, __shfl_down(a, off, 64));
    if ((tid & 63) == 0) s_red[tid >> 6] = a;
    __syncthreads();
    return fmaxf(fmaxf(fmaxf(s_red[0], s_red[1]), fmaxf(s_red[2], s_red[3])),
                 fmaxf(fmaxf(s_red[4], s_red[5]), fmaxf(s_red[6], s_red[7])));
}

__global__ __launch_bounds__(THR, 4) void bottom_up(
    const float* __restrict__ ent,      // [BS,NSEQ,NBOX]
    float*       __restrict__ ea,       // [BS,NSEQ,NBOX] (d_out)
    const float* __restrict__ spo,      // [BS,NSEQ,NBOX,NCTX]
    const int*   __restrict__ ctx,      // [BS,NBOX,NCTX]
    const int*   __restrict__ roi_cls,  // [BS,NBOX]
    const float* __restrict__ rm,       // [BS,NBOX,NCTX]
    const float* __restrict__ wc,       // [BS,NSEQ,NBOX]
    const int*   __restrict__ trav,     // [BS,MAXLEN]
    const int*   __restrict__ adj,      // [BS,NSEQ,NSEQ]
    int*         __restrict__ midx,
    float*       __restrict__ araw,
    float*       __restrict__ oldrow,
    unsigned*    __restrict__ cnt)
{
    const int blk  = blockIdx.x;
    const int b    = blk >> 4;      // batch
    const int sub  = blk & 15;      // sub-block within batch
    const int tid  = threadIdx.x;
    const int wave = tid >> 6;
    const int lane = tid & 63;

    __shared__ __align__(16) float cae[NSEQ][ROWP];
    __shared__ float s_fin[NBOX];
    __shared__ float s_red[8];
    __shared__ int   s_childJ[NSEQ];

    // one-time: zero cae pad columns (never overwritten afterwards)
    if (tid < NSEQ * 4) cae[tid >> 2][NBOX + (tid & 3)] = 0.f;

    // copy this batch's ea slice (nothing reads ea rows before barrier 0
    // except via ent / s_fin substitutions)
    {
        const int idx = sub * THR + tid;                 // 0..8191
        if (idx < NSEQ * NBOX / 4)
            ((float4*)(ea + (size_t)b * NSEQ * NBOX))[idx] =
                ((const float4*)(ent + (size_t)b * NSEQ * NBOX))[idx];
    }

    // build midx (= rm ? ctx : sentinel) for owned i's, once
    for (int k = wave; ; k += 8) {
        const int i = sub + 16 * k;
        if (i >= NBOX) break;
        if (lane < NB4) {
            const size_t bi = (size_t)b * NBOX + i;
            const int4   ix = ((const int4*)  (ctx + bi * NCTX))[lane];
            const float4 m4 = ((const float4*)(rm  + bi * NCTX))[lane];
            int4 mi;
            mi.x = (m4.x != 0.f) ? ix.x : NBOX;
            mi.y = (m4.y != 0.f) ? ix.y : NBOX;
            mi.z = (m4.z != 0.f) ? ix.z : NBOX;
            mi.w = (m4.w != 0.f) ? ix.w : NBOX;
            ((int4*)(midx + bi * NCTX))[lane] = mi;
        }
    }

    int p_prev = -1, nch_prev = 0;

    for (int t = 0; t < MAXLEN; ++t) {
        const float* src = (t == 0) ? ent : ea;
        const bool prevvalid = (p_prev >= 0 && nch_prev > 0);

        // ---- parse step-t adjacency (full exec, wave-parallel)
        const int p = trav[b * MAXLEN + t];
        int e = -1;
        if (p >= 0 && lane < NSEQ)
            e = adj[((size_t)b * NSEQ + p) * NSEQ + lane];
        const unsigned long long mask = __ballot(e >= 0);
        const int nch = __popcll(mask);
        int ec = 0;
        if (nch > 0) {
            unsigned long long m = mask;
            const int lim = (lane < NSEQ) ? lane : NSEQ;
            for (int k = 0; k < lim; ++k) m &= (m - 1);
            const int j0 = __ffsll(mask) - 1;
            const int jn = m ? (__ffsll(m) - 1) : j0;
            const int jc = (lane < nch) ? jn : j0;
            ec = __shfl(e, jc);                          // full-exec: safe
            if (wave == 0 && lane < nch) s_childJ[lane] = jc;
        }

        // ---- redundant finalize of step t-1 -> s_fin (all blocks of batch)
        if (prevvalid) {
            float u = 0.f, a = 0.f;
            if (tid < NBOX) {
                const float old = oldrow[(size_t)((t - 1) & 1) * BS * NBOX + b * NBOX + tid];
                const float w   = wc[((size_t)b * NSEQ + p_prev) * NBOX + tid];
                u = old + (araw[(size_t)(t - 1) * BS * NBOX + b * NBOX + tid]
                           + (float)nch_prev * EPSV) * w;
                a = fabsf(u);
            }
            float norm = blockmax(a, s_red, tid);
            norm = (norm <= 1.0f) ? 1.0f : norm;
            if (tid < NBOX) {
                float v = u / norm;
                if (roi_cls[b * NBOX + tid] == -1) v = -1.0f;
                s_fin[tid] = v;
                if (sub == 0)
                    ea[((size_t)b * NSEQ + p_prev) * NBOX + tid] = v;  // commit
            }
            __syncthreads();   // s_fin visible to staging / snapshot
        }

        // ---- snapshot current parent row for next step's finalize (sub 0)
        if (p >= 0 && sub == 0 && tid < NBOX) {
            float sv = (prevvalid && p == p_prev)
                       ? s_fin[tid]
                       : src[((size_t)b * NSEQ + p) * NBOX + tid];
            oldrow[(size_t)(t & 1) * BS * NBOX + b * NBOX + tid] = sv;
        }

        if (nch > 0) {
            __syncthreads();   // s_childJ ready; cae free (prev step synced out)

            // ---- stage child rows * kcls into LDS
            for (int t2 = tid; t2 < nch * NBOX; t2 += THR) {
                const int n = t2 / NBOX;
                const int k = t2 - n * NBOX;
                const int j = s_childJ[n];
                float v = (prevvalid && j == p_prev)
                          ? s_fin[k]
                          : src[((size_t)b * NSEQ + j) * NBOX + k];
                cae[n][k] = (roi_cls[b * NBOX + k] != -1) ? v : 0.f;
            }
            __syncthreads();

            // ---- gather-dot for owned i's (one i per wave per round)
            for (int k = wave; ; k += 8) {
                const int i = sub + 16 * k;
                if (i >= NBOX) break;
                float acc = 0.f;
                if (lane < NB4) {
                    const size_t bi = (size_t)b * NBOX + i;
                    const int4 mi = ((const int4*)(midx + bi * NCTX))[lane];
                    const float* sb = spo + ((size_t)b * NSEQ * NBOX + i) * NCTX;
                    const size_t st = (size_t)NBOX * NCTX;
                    const int e0 = __shfl(ec, 0), e1 = __shfl(ec, 1), e2 = __shfl(ec, 2);
                    float4 s0 = ((const float4*)(sb + (size_t)e0 * st))[lane];
                    float4 s1 = ((const float4*)(sb + (size_t)e1 * st))[lane];
                    float4 s2 = ((const float4*)(sb + (size_t)e2 * st))[lane];
                    float4 a4 = make_float4(0.f, 0.f, 0.f, 0.f);
                    for (int n = 0; n < nch; ++n) {
                        const int ep = __shfl(ec, (n + 3 < nch) ? n + 3 : 0);
                        float4 nx = ((const float4*)(sb + (size_t)ep * st))[lane];
                        a4.x = fmaf(cae[n][mi.x], s0.x, a4.x);
                        a4.y = fmaf(cae[n][mi.y], s0.y, a4.y);
                        a4.z = fmaf(cae[n][mi.z], s0.z, a4.z);
                        a4.w = fmaf(cae[n][mi.w], s0.w, a4.w);
                        s0 = s1; s1 = s2; s2 = nx;
                    }
                    acc = (a4.x + a4.y) + (a4.z + a4.w);
                }
                #pragma unroll
                for (int off = 32; off >= 1; off >>= 1)
                    acc += __shfl_down(acc, off, 64);
                if (lane == 0) {
                    float kci = (roi_cls[b * NBOX + i] != -1) ? 1.0f : 0.0f;
                    araw[(size_t)t * BS * NBOX + b * NBOX + i] = kci * acc;
                }
            }
        }

        // ---- per-batch barrier (unconditional)
        __syncthreads();
        if (tid == 0) {
            __threadfence();
            unsigned* c = &cnt[(t * BS + b) * 16];
            atomicAdd(c, 1u);
            while (atomicAdd(c, 0u) < (unsigned)BPB)
                __builtin_amdgcn_s_sleep(2);
            __threadfence();
        }
        __syncthreads();

        p_prev = p; nch_prev = nch;
    }

    // ---- tail: finalize last step (sub-block 0 of each batch only)
    if (sub == 0 && p_prev >= 0 && nch_prev > 0) {
        float u = 0.f, a = 0.f;
        if (tid < NBOX) {
            const float old = oldrow[(size_t)((MAXLEN - 1) & 1) * BS * NBOX + b * NBOX + tid];
            const float w   = wc[((size_t)b * NSEQ + p_prev) * NBOX + tid];
            u = old + (araw[(size_t)(MAXLEN - 1) * BS * NBOX + b * NBOX + tid]
                       + (float)nch_prev * EPSV) * w;
            a = fabsf(u);
        }
        float norm = blockmax(a, s_red, tid);
        norm = (norm <= 1.0f) ? 1.0f : norm;
        if (tid < NBOX) {
            float v = u / norm;
            if (roi_cls[b * NBOX + tid] == -1) v = -1.0f;
            ea[((size_t)b * NSEQ + p_prev) * NBOX + tid] = v;
        }
    }
}

extern "C" void kernel_launch(void* const* d_in, const int* in_sizes, int n_in,
                              void* d_out, int out_size, void* d_ws, size_t ws_size,
                              hipStream_t stream) {
    const int*   trav = (const int*)  d_in[0];
    const int*   adj  = (const int*)  d_in[1];
    const float* ent  = (const float*)d_in[2];
    const float* spo  = (const float*)d_in[3];
    const int*   ctx  = (const int*)  d_in[4];
    const int*   roi  = (const int*)  d_in[5];
    const float* rm   = (const float*)d_in[6];
    const float* wc   = (const float*)d_in[7];

    float* ea = (float*)d_out;

    size_t off = MIDX_ELEMS;
    int*      midx   = (int*)d_ws;
    float*    araw   = (float*)d_ws + off;      off += (size_t)MAXLEN * BS * NBOX;
    float*    oldrow = (float*)d_ws + off;      off += (size_t)2 * BS * NBOX;
    unsigned* cnt    = (unsigned*)((float*)d_ws + off);

    zero_cnt<<<(CNT_N + 255) / 256, 256, 0, stream>>>(cnt);
    bottom_up<<<GRID, THR, 0, stream>>>(
        ent, ea, spo, ctx, roi, rm, wc, trav, adj, midx, araw, oldrow, cnt);
}

// Round 9
// 232.591 us; speedup vs baseline: 1.1813x; 1.1813x over previous
//
#include <hip/hip_runtime.h>

#define NSEQ   24
#define NBOX   196
#define NCTX   196
#define MAXLEN 6
#define EPSV   1e-6f
#define BS     32

#define TILES  25    // i-tiles per batch; 8 waves/block, 1 i per wave
#define K1T    512
#define NB4    49    // float4 chunks per 196-row
#define ROWP   200   // padded cae row: 196 data + 4 zeros (sentinel idx 196)

// ws layout: midx u8 [BS*NBOX*NCTX] | araw f32 [BS*NBOX] | done u32 [MAXLEN*BS*16]
#define MIDX_BYTES ((size_t)BS * NBOX * NCTX)   // 1,229,312 B (16-aligned)
#define DONE_N     (MAXLEN * BS * 16)

__global__ void init_ws(unsigned* __restrict__ done) {
    int i = blockIdx.x * blockDim.x + threadIdx.x;
    if (i < DONE_N) done[i] = 0u;
}

// mode: 0 = compute midx from ctx+rm (no store)   [fallback]
//       1 = compute and store u8 midx (step 0)
//       2 = load u8 midx (steps 1..5)
__global__ __launch_bounds__(K1T, 6) void step_compute(
    const float* __restrict__ src,      // ent (step 0) or ea
    float*       __restrict__ ea,       // [BS,NSEQ,NBOX] (d_out)
    const float* __restrict__ spo,      // [BS,NSEQ,NBOX,NCTX]
    const int*   __restrict__ ctx,      // [BS,NBOX,NCTX]
    const int*   __restrict__ roi_cls,  // [BS,NBOX]
    const float* __restrict__ rm,       // [BS,NBOX,NCTX]
    const float* __restrict__ wc,       // [BS,NSEQ,NBOX]
    const int*   __restrict__ trav,     // [BS,MAXLEN]
    const int*   __restrict__ adj,      // [BS,NSEQ,NSEQ]
    unsigned char* __restrict__ midx,   // ws
    float*       __restrict__ araw,     // ws [BS,NBOX]
    unsigned*    __restrict__ done,     // ws [MAXLEN,BS,16]
    int step, int mode)
{
    const int b    = blockIdx.x / TILES;
    const int tile = blockIdx.x % TILES;
    const int tid  = threadIdx.x;
    const int wave = tid >> 6;
    const int lane = tid & 63;

    __shared__ __align__(16) float cae[NSEQ][ROWP];
    __shared__ float s_red[8];
    __shared__ int   s_childJ[NSEQ];
    __shared__ int   s_flag;

    // ---- step-0: copy OWN batch's ea slice (tiles 0..2 suffice: 3*512 >= 1176)
    if (step == 0) {
        const int idx = tile * K1T + tid;
        if (idx < NSEQ * NBOX / 4)
            ((float4*)(ea + (size_t)b * NSEQ * NBOX))[idx] =
                ((const float4*)(src + (size_t)b * NSEQ * NBOX))[idx];
    }

    // ---- wave-parallel adjacency parse (full exec)
    const int p = trav[b * MAXLEN + step];
    int e = -1;
    if (p >= 0 && lane < NSEQ)
        e = adj[((size_t)b * NSEQ + p) * NSEQ + lane];
    const unsigned long long mask = __ballot(e >= 0);
    const int nch = __popcll(mask);
    int ec = 0;
    if (nch > 0) {
        unsigned long long m = mask;
        const int lim = (lane < NSEQ) ? lane : NSEQ;
        for (int k = 0; k < lim; ++k) m &= (m - 1);
        const int j0 = __ffsll(mask) - 1;
        const int jn = m ? (__ffsll(m) - 1) : j0;
        const int jc = (lane < nch) ? jn : j0;   // lanes >= nch: child 0 (pad)
        ec = __shfl(e, jc);                      // full-exec shfl: safe
        if (wave == 0 && lane < nch) s_childJ[lane] = jc;
    }

    // ---- per-wave i; mask-index vector (build/store/load midx BEFORE any return)
    const int i = tile * 8 + wave;
    int4 mi = make_int4(NBOX, NBOX, NBOX, NBOX);
    if (i < NBOX && lane < NB4) {
        const size_t bi = (size_t)b * NBOX + i;
        if (mode == 2) {
            const uchar4 u = ((const uchar4*)(midx + bi * NCTX))[lane];
            mi = make_int4(u.x, u.y, u.z, u.w);
        } else {
            const int4   ix = ((const int4*)  (ctx + bi * NCTX))[lane];
            const float4 m4 = ((const float4*)(rm  + bi * NCTX))[lane];
            mi.x = (m4.x != 0.f) ? ix.x : NBOX;
            mi.y = (m4.y != 0.f) ? ix.y : NBOX;
            mi.z = (m4.z != 0.f) ? ix.z : NBOX;
            mi.w = (m4.w != 0.f) ? ix.w : NBOX;
            if (mode == 1)
                ((uchar4*)(midx + bi * NCTX))[lane] =
                    make_uchar4((unsigned char)mi.x, (unsigned char)mi.y,
                                (unsigned char)mi.z, (unsigned char)mi.w);
        }
    }

    if (nch == 0) return;   // uniform across block; no barrier crossed yet

    __syncthreads();        // s_childJ visible

    // ---- stage child rows * kcls into LDS (vectorized; quad 49 = zero pad)
    for (int n = wave; n < nch; n += 8) {
        const int j = s_childJ[n];
        if (lane < 50) {
            float4 v = make_float4(0.f, 0.f, 0.f, 0.f);
            if (lane < NB4) {
                const float4 e4 = ((const float4*)(src + ((size_t)b * NSEQ + j) * NBOX))[lane];
                const int4   r4 = ((const int4*)(roi_cls + b * NBOX))[lane];
                v.x = (r4.x != -1) ? e4.x : 0.f;
                v.y = (r4.y != -1) ? e4.y : 0.f;
                v.z = (r4.z != -1) ? e4.z : 0.f;
                v.w = (r4.w != -1) ? e4.w : 0.f;
            }
            ((float4*)&cae[n][0])[lane] = v;
        }
    }
    __syncthreads();

    // ---- gather-dot: one i per wave, 3-deep rotating spo prefetch
    if (i < NBOX) {
        float acc = 0.f;
        if (lane < NB4) {
            const float* sb = spo + ((size_t)b * NSEQ * NBOX + i) * NCTX;
            const size_t st = (size_t)NBOX * NCTX;
            const int e0 = __shfl(ec, 0), e1 = __shfl(ec, 1), e2 = __shfl(ec, 2);
            float4 s0 = ((const float4*)(sb + (size_t)e0 * st))[lane];
            float4 s1 = ((const float4*)(sb + (size_t)e1 * st))[lane];
            float4 s2 = ((const float4*)(sb + (size_t)e2 * st))[lane];
            float4 a4 = make_float4(0.f, 0.f, 0.f, 0.f);
            for (int n = 0; n < nch; ++n) {
                const int ep = __shfl(ec, n + 3);   // n+3 <= 26 < 49: active lane
                float4 nx = ((const float4*)(sb + (size_t)ep * st))[lane];
                a4.x = fmaf(cae[n][mi.x], s0.x, a4.x);
                a4.y = fmaf(cae[n][mi.y], s0.y, a4.y);
                a4.z = fmaf(cae[n][mi.z], s0.z, a4.z);
                a4.w = fmaf(cae[n][mi.w], s0.w, a4.w);
                s0 = s1; s1 = s2; s2 = nx;
            }
            acc = (a4.x + a4.y) + (a4.z + a4.w);
        }
        #pragma unroll
        for (int off = 32; off >= 1; off >>= 1)
            acc += __shfl_down(acc, off, 64);
        if (lane == 0) {
            float kci = (roi_cls[b * NBOX + i] != -1) ? 1.0f : 0.0f;
            araw[b * NBOX + i] = kci * acc;
        }
    }

    // ---- last-block-of-batch does the finalize (no spinning)
    __syncthreads();                       // drains this block's araw stores
    if (tid == 0) {
        __threadfence();                   // release this block's stores
        const unsigned old = atomicAdd(&done[(step * BS + b) * 16], 1u);
        const int win = (old == TILES - 1);
        if (win) __threadfence();          // acquire all blocks' stores
        s_flag = win;
    }
    __syncthreads();
    if (!s_flag) return;

    // epilogue: finalize row p of batch b (whole winner block)
    float u = 0.f, a = 0.f;
    if (tid < NBOX) {
        const float sub = ea[((size_t)b * NSEQ + p) * NBOX + tid];
        const float w   = wc[((size_t)b * NSEQ + p) * NBOX + tid];
        u = sub + (araw[b * NBOX + tid] + (float)nch * EPSV) * w;
        a = fabsf(u);
    }
    #pragma unroll
    for (int off = 32; off >= 1; off >>= 1)
        a = fmaxf(a, __shfl_down(a, off, 64));
    if ((tid & 63) == 0) s_red[tid >> 6] = a;
    __syncthreads();
    float norm = fmaxf(fmaxf(fmaxf(s_red[0], s_red[1]), fmaxf(s_red[2], s_red[3])),
                       fmaxf(fmaxf(s_red[4], s_red[5]), fmaxf(s_red[6], s_red[7])));
    norm = (norm <= 1.0f) ? 1.0f : norm;
    if (tid < NBOX) {
        float v = u / norm;
        if (roi_cls[b * NBOX + tid] == -1) v = -1.0f;
        ea[((size_t)b * NSEQ + p) * NBOX + tid] = v;
    }
}

extern "C" void kernel_launch(void* const* d_in, const int* in_sizes, int n_in,
                              void* d_out, int out_size, void* d_ws, size_t ws_size,
                              hipStream_t stream) {
    const int*   trav = (const int*)  d_in[0];
    const int*   adj  = (const int*)  d_in[1];
    const float* ent  = (const float*)d_in[2];
    const float* spo  = (const float*)d_in[3];
    const int*   ctx  = (const int*)  d_in[4];
    const int*   roi  = (const int*)  d_in[5];
    const float* rm   = (const float*)d_in[6];
    const float* wc   = (const float*)d_in[7];

    float* ea = (float*)d_out;

    // ws layout
    const size_t need = MIDX_BYTES + (size_t)BS * NBOX * 4 + (size_t)DONE_N * 4;
    const bool ws_ok = ws_size >= need;
    unsigned char* midx;
    float*         araw;
    unsigned*      done;
    if (ws_ok) {
        midx = (unsigned char*)d_ws;
        araw = (float*)((char*)d_ws + MIDX_BYTES);
        done = (unsigned*)((char*)d_ws + MIDX_BYTES + (size_t)BS * NBOX * 4);
    } else {
        midx = (unsigned char*)d_ws;                      // unused in mode 0
        araw = (float*)d_ws;
        done = (unsigned*)((char*)d_ws + (size_t)BS * NBOX * 4);
    }

    init_ws<<<(DONE_N + 255) / 256, 256, 0, stream>>>(done);

    for (int t = 0; t < MAXLEN; ++t) {
        const int mode = ws_ok ? (t == 0 ? 1 : 2) : 0;
        step_compute<<<BS * TILES, K1T, 0, stream>>>(
            t == 0 ? ent : ea, ea, spo, ctx, roi, rm, wc, trav, adj,
            midx, araw, done, t, mode);
    }
}

// Round 10
// 99.580 us; speedup vs baseline: 2.7591x; 2.3357x over previous
//
#include <hip/hip_runtime.h>

#define NSEQ   24
#define NBOX   196
#define NCTX   196
#define MAXLEN 6
#define EPSV   1e-6f
#define BS     32

#define TILES  25    // i-tiles per batch; 8 waves/block, 1 i per wave
#define K1T    512
#define NB4    49    // float4 chunks per 196-row
#define ROWP   200   // padded cae row: 196 data + 4 zeros (sentinel idx 196)

// ws layout: midx u8 [BS*NBOX*NCTX] | araw f32 [BS*NBOX]
#define MIDX_BYTES ((size_t)BS * NBOX * NCTX)   // 1,229,312 B (16-aligned)

// mode: 0 = compute midx from ctx+rm (no store)   [fallback if ws tiny]
//       1 = compute and store u8 midx (step 0)
//       2 = load u8 midx (steps 1..5)
__global__ __launch_bounds__(K1T, 6) void step_compute(
    const float* __restrict__ src,      // ent (step 0) or ea
    float*       __restrict__ ea,       // [BS,NSEQ,NBOX] (d_out)
    const float* __restrict__ spo,      // [BS,NSEQ,NBOX,NCTX]
    const int*   __restrict__ ctx,      // [BS,NBOX,NCTX]
    const int*   __restrict__ roi_cls,  // [BS,NBOX]
    const float* __restrict__ rm,       // [BS,NBOX,NCTX]
    const int*   __restrict__ trav,     // [BS,MAXLEN]
    const int*   __restrict__ adj,      // [BS,NSEQ,NSEQ]
    unsigned char* __restrict__ midx,   // ws
    float*       __restrict__ araw,     // ws [BS,NBOX]
    int step, int mode)
{
    const int b    = blockIdx.x / TILES;
    const int tile = blockIdx.x % TILES;
    const int tid  = threadIdx.x;
    const int wave = tid >> 6;
    const int lane = tid & 63;

    __shared__ __align__(16) float cae[NSEQ][ROWP];
    __shared__ int s_childJ[NSEQ];

    // ---- fused ent -> ea copy (step 0; nothing reads ea this dispatch)
    if (step == 0) {
        const int total4 = BS * NSEQ * NBOX / 4;
        int idx = blockIdx.x * K1T + tid;
        if (idx < total4) ((float4*)ea)[idx] = ((const float4*)src)[idx];
    }

    // ---- wave-parallel adjacency parse (full exec)
    const int p = trav[b * MAXLEN + step];
    int e = -1;
    if (p >= 0 && lane < NSEQ)
        e = adj[((size_t)b * NSEQ + p) * NSEQ + lane];
    const unsigned long long mask = __ballot(e >= 0);
    const int nch = __popcll(mask);
    int ec = 0;
    if (nch > 0) {
        unsigned long long m = mask;
        const int lim = (lane < NSEQ) ? lane : NSEQ;
        for (int k = 0; k < lim; ++k) m &= (m - 1);
        const int j0 = __ffsll(mask) - 1;
        const int jn = m ? (__ffsll(m) - 1) : j0;
        const int jc = (lane < nch) ? jn : j0;   // lanes >= nch: child 0 (pad)
        ec = __shfl(e, jc);                      // full-exec shfl: safe
        if (wave == 0 && lane < nch) s_childJ[lane] = jc;
    }

    // ---- per-wave i; mask-index vector (built/stored/loaded BEFORE any return
    //      so step-0 writes midx for all i even when nch==0)
    const int i = tile * 8 + wave;
    int4 mi = make_int4(NBOX, NBOX, NBOX, NBOX);
    if (i < NBOX && lane < NB4) {
        const size_t bi = (size_t)b * NBOX + i;
        if (mode == 2) {
            const uchar4 u = ((const uchar4*)(midx + bi * NCTX))[lane];
            mi = make_int4(u.x, u.y, u.z, u.w);
        } else {
            const int4   ix = ((const int4*)  (ctx + bi * NCTX))[lane];
            const float4 m4 = ((const float4*)(rm  + bi * NCTX))[lane];
            mi.x = (m4.x != 0.f) ? ix.x : NBOX;
            mi.y = (m4.y != 0.f) ? ix.y : NBOX;
            mi.z = (m4.z != 0.f) ? ix.z : NBOX;
            mi.w = (m4.w != 0.f) ? ix.w : NBOX;
            if (mode == 1)
                ((uchar4*)(midx + bi * NCTX))[lane] =
                    make_uchar4((unsigned char)mi.x, (unsigned char)mi.y,
                                (unsigned char)mi.z, (unsigned char)mi.w);
        }
    }

    if (nch == 0) return;   // uniform across block; no barrier crossed yet

    __syncthreads();        // s_childJ visible

    // ---- stage child rows * kcls into LDS (float4; quad 49 writes zero pad)
    for (int n = wave; n < nch; n += 8) {
        const int j = s_childJ[n];
        if (lane < 50) {
            float4 v = make_float4(0.f, 0.f, 0.f, 0.f);
            if (lane < NB4) {
                const float4 e4 = ((const float4*)(src + ((size_t)b * NSEQ + j) * NBOX))[lane];
                const int4   r4 = ((const int4*)(roi_cls + b * NBOX))[lane];
                v.x = (r4.x != -1) ? e4.x : 0.f;
                v.y = (r4.y != -1) ? e4.y : 0.f;
                v.z = (r4.z != -1) ? e4.z : 0.f;
                v.w = (r4.w != -1) ? e4.w : 0.f;
            }
            ((float4*)&cae[n][0])[lane] = v;
        }
    }
    __syncthreads();

    // ---- gather-dot: one i per wave, 3-deep rotating spo prefetch
    if (i < NBOX) {
        float acc = 0.f;
        if (lane < NB4) {
            const float* sb = spo + ((size_t)b * NSEQ * NBOX + i) * NCTX;
            const size_t st = (size_t)NBOX * NCTX;
            const int e0 = __shfl(ec, 0), e1 = __shfl(ec, 1), e2 = __shfl(ec, 2);
            float4 s0 = ((const float4*)(sb + (size_t)e0 * st))[lane];
            float4 s1 = ((const float4*)(sb + (size_t)e1 * st))[lane];
            float4 s2 = ((const float4*)(sb + (size_t)e2 * st))[lane];
            float4 a4 = make_float4(0.f, 0.f, 0.f, 0.f);
            for (int n = 0; n < nch; ++n) {
                const int ep = __shfl(ec, n + 3);   // n+3 <= 26 < 49: active lane
                float4 nx = ((const float4*)(sb + (size_t)ep * st))[lane];
                a4.x = fmaf(cae[n][mi.x], s0.x, a4.x);
                a4.y = fmaf(cae[n][mi.y], s0.y, a4.y);
                a4.z = fmaf(cae[n][mi.z], s0.z, a4.z);
                a4.w = fmaf(cae[n][mi.w], s0.w, a4.w);
                s0 = s1; s1 = s2; s2 = nx;
            }
            acc = (a4.x + a4.y) + (a4.z + a4.w);
        }
        #pragma unroll
        for (int off = 32; off >= 1; off >>= 1)
            acc += __shfl_down(acc, off, 64);
        if (lane == 0) {
            float kci = (roi_cls[b * NBOX + i] != -1) ? 1.0f : 0.0f;
            araw[b * NBOX + i] = kci * acc;
        }
    }
}

// ------------------------------------------------- per-step: finalize + write
__global__ __launch_bounds__(256) void step_finalize(
    float*       __restrict__ ea,       // [BS,NSEQ,NBOX] in/out
    const float* __restrict__ araw,     // ws [BS,NBOX]
    const float* __restrict__ wc,       // [BS,NSEQ,NBOX]
    const int*   __restrict__ roi_cls,  // [BS,NBOX]
    const int*   __restrict__ trav,     // [BS,MAXLEN]
    const int*   __restrict__ adj,      // [BS,NSEQ,NSEQ]
    int step)
{
    const int b   = blockIdx.x;
    const int tid = threadIdx.x;
    const int p   = trav[b * MAXLEN + step];

    int nch = 0;
    if (p >= 0) {
        const int* arow = adj + ((size_t)b * NSEQ + p) * NSEQ;
        for (int j = 0; j < NSEQ; ++j) nch += (arow[j] >= 0) ? 1 : 0;
    }
    if (p < 0 || nch == 0) return;  // row stays unchanged

    float upd = 0.0f, a = 0.0f;
    if (tid < NBOX) {
        const float sub = ea[((size_t)b * NSEQ + p) * NBOX + tid];
        const float w   = wc[((size_t)b * NSEQ + p) * NBOX + tid];
        upd = sub + (araw[b * NBOX + tid] + (float)nch * EPSV) * w;
        a = fabsf(upd);
    }
    #pragma unroll
    for (int off = 32; off >= 1; off >>= 1)
        a = fmaxf(a, __shfl_down(a, off, 64));
    __shared__ float wmax[4];
    if ((tid & 63) == 0) wmax[tid >> 6] = a;
    __syncthreads();
    float norm = fmaxf(fmaxf(wmax[0], wmax[1]), fmaxf(wmax[2], wmax[3]));
    norm = (norm <= 1.0f) ? 1.0f : norm;
    if (tid < NBOX) {
        float val = upd / norm;
        if (roi_cls[b * NBOX + tid] == -1) val = -1.0f;
        ea[((size_t)b * NSEQ + p) * NBOX + tid] = val;
    }
}

extern "C" void kernel_launch(void* const* d_in, const int* in_sizes, int n_in,
                              void* d_out, int out_size, void* d_ws, size_t ws_size,
                              hipStream_t stream) {
    const int*   trav = (const int*)  d_in[0];
    const int*   adj  = (const int*)  d_in[1];
    const float* ent  = (const float*)d_in[2];
    const float* spo  = (const float*)d_in[3];
    const int*   ctx  = (const int*)  d_in[4];
    const int*   roi  = (const int*)  d_in[5];
    const float* rm   = (const float*)d_in[6];
    const float* wc   = (const float*)d_in[7];

    float* ea = (float*)d_out;

    const size_t need = MIDX_BYTES + (size_t)BS * NBOX * 4;
    const bool ws_ok = ws_size >= need;
    unsigned char* midx = (unsigned char*)d_ws;
    float* araw = ws_ok ? (float*)((char*)d_ws + MIDX_BYTES) : (float*)d_ws;

    for (int t = 0; t < MAXLEN; ++t) {
        const int mode = ws_ok ? (t == 0 ? 1 : 2) : 0;
        step_compute<<<BS * TILES, K1T, 0, stream>>>(
            t == 0 ? ent : ea, ea, spo, ctx, roi, rm, trav, adj,
            midx, araw, t, mode);
        step_finalize<<<BS, 256, 0, stream>>>(
            ea, araw, wc, roi, trav, adj, t);
    }
}